// Round 3
// baseline (988.674 us; speedup 1.0000x reference)
//
#include <hip/hip_runtime.h>
#include <hip/hip_bf16.h>

// GRU: V=50000, E=256, H=256, B=64, T=512
// out: outputs[T,B,H] f32 then h_last[1,B,H] f32 (concat flat)

#define T_SEQ 512
#define B_SZ 64
#define E_DIM 256
#define H_DIM 256
#define G3 768   // 3*H

typedef _Float16 half2v __attribute__((ext_vector_type(2)));

#if __has_builtin(__builtin_amdgcn_fdot2)
#define FDOT2(a, b, c) __builtin_amdgcn_fdot2((a), (b), (c), false)
#else
#define FDOT2(a, b, c) ((c) + (float)(a).x * (float)(b).x + (float)(a).y * (float)(b).y)
#endif

// ---------------- Kernel A: x_proj = gather(emb, input) @ W_ih^T + b_ih ----
#define BM 64
#define BN 64
#define BK 32
#define LDSPAD 4

__global__ __launch_bounds__(256) void xproj_kernel(
    const int* __restrict__ input,
    const float* __restrict__ emb,
    const float* __restrict__ W_ih,
    const float* __restrict__ b_ih,
    float* __restrict__ xp)
{
    __shared__ float As[BM][BK + LDSPAD];
    __shared__ float Bs[BN][BK + LDSPAD];
    __shared__ int rowidx[BM];

    const int tid = threadIdx.x;
    const int m0 = blockIdx.x * BM;
    const int n0 = blockIdx.y * BN;

    if (tid < BM) {
        int m = m0 + tid;
        int t = m >> 6;
        int b = m & 63;
        rowidx[tid] = input[b * T_SEQ + t];
    }
    __syncthreads();

    float acc[4][4] = {};
    const int ty = tid >> 4;
    const int tx = tid & 15;

    for (int k0 = 0; k0 < E_DIM; k0 += BK) {
        #pragma unroll
        for (int i = 0; i < 2; ++i) {
            int f4 = tid * 2 + i;
            int row = f4 >> 3;
            int c4  = (f4 & 7) * 4;
            float4 v = *reinterpret_cast<const float4*>(
                emb + (size_t)rowidx[row] * E_DIM + k0 + c4);
            *reinterpret_cast<float4*>(&As[row][c4]) = v;
        }
        #pragma unroll
        for (int i = 0; i < 2; ++i) {
            int f4 = tid * 2 + i;
            int row = f4 >> 3;
            int c4  = (f4 & 7) * 4;
            float4 v = *reinterpret_cast<const float4*>(
                W_ih + (size_t)(n0 + row) * E_DIM + k0 + c4);
            *reinterpret_cast<float4*>(&Bs[row][c4]) = v;
        }
        __syncthreads();

        #pragma unroll
        for (int kk = 0; kk < BK; kk += 4) {
            float4 a[4], b[4];
            #pragma unroll
            for (int i = 0; i < 4; ++i)
                a[i] = *reinterpret_cast<const float4*>(&As[ty * 4 + i][kk]);
            #pragma unroll
            for (int j = 0; j < 4; ++j)
                b[j] = *reinterpret_cast<const float4*>(&Bs[tx * 4 + j][kk]);
            #pragma unroll
            for (int i = 0; i < 4; ++i)
                #pragma unroll
                for (int j = 0; j < 4; ++j)
                    acc[i][j] += a[i].x * b[j].x + a[i].y * b[j].y +
                                 a[i].z * b[j].z + a[i].w * b[j].w;
        }
        __syncthreads();
    }

    #pragma unroll
    for (int i = 0; i < 4; ++i) {
        int m = m0 + ty * 4 + i;
        int n = n0 + tx * 4;
        float4 o;
        o.x = acc[i][0] + b_ih[n + 0];
        o.y = acc[i][1] + b_ih[n + 1];
        o.z = acc[i][2] + b_ih[n + 2];
        o.w = acc[i][3] + b_ih[n + 3];
        *reinterpret_cast<float4*>(&xp[(size_t)m * G3 + n]) = o;
    }
}

// ---------------- Kernel B: GRU scan, weights register-resident ------------
// 64 blocks (one per batch), 512 threads = 8 waves, launch_bounds(512,2)
// => 256-VGPR cap. Thread (jj = tid>>2, q = tid&3) owns 6 rows
// {jj + 128*s, s=0..5} x k-slice [64q, 64q+64) of W_hh as 192 f16x2 VGPRs.
// Partials reduced across the quad (q=0..3) via __shfl_xor (DPP) — no LDS
// partial buffer. h double-buffered in LDS (2x512B) => ONE barrier/step.
// Weight chunks pre-rotated by (i8+2q)&7 at load time so the 4 q-lanes of a
// quad read disjoint LDS bank groups (conflict-free broadcast reads) while
// all weight register indices stay compile-time constant.
__device__ __forceinline__ float fast_sigmoid(float x) {
    float e = __expf(-x);
    return __builtin_amdgcn_rcpf(1.0f + e);
}
__device__ __forceinline__ float fast_tanh(float x) {
    x = fminf(x, 8.0f);
    float e = __expf(2.0f * x);
    return (e - 1.0f) * __builtin_amdgcn_rcpf(e + 1.0f);
}

__global__ __launch_bounds__(512, 2) void gru_scan_kernel(
    const float* __restrict__ xp,    // [T*B, 768]
    const float* __restrict__ W_hh,  // [768, 256]
    const float* __restrict__ b_hh,  // [768]
    float* __restrict__ out)         // outputs [T*B*256] ++ h_last [64*256]
{
    const int b   = blockIdx.x;    // batch element
    const int tid = threadIdx.x;
    const int jj  = tid >> 2;      // 0..127 : column pair (jj, jj+128)
    const int q   = tid & 3;       // k-slice [64q, 64q+64)

    __shared__ __align__(16) _Float16 hs[2][H_DIM];  // double-buffered h (f16)

    // ---- prologue: weights -> registers, f16, chunk-rotated by q ----
    half2v w[6][32];
    #pragma unroll
    for (int s = 0; s < 6; ++s) {
        const float* wr = W_hh + (size_t)(jj + 128 * s) * H_DIM + q * 64;
        #pragma unroll
        for (int i8 = 0; i8 < 8; ++i8) {
            const int src = ((i8 + 2 * q) & 7) * 8;   // rotated source chunk
            float4 f0 = *reinterpret_cast<const float4*>(wr + src);
            float4 f1 = *reinterpret_cast<const float4*>(wr + src + 4);
            w[s][i8 * 4 + 0] = half2v{(_Float16)f0.x, (_Float16)f0.y};
            w[s][i8 * 4 + 1] = half2v{(_Float16)f0.z, (_Float16)f0.w};
            w[s][i8 * 4 + 2] = half2v{(_Float16)f1.x, (_Float16)f1.y};
            w[s][i8 * 4 + 3] = half2v{(_Float16)f1.z, (_Float16)f1.w};
        }
    }
    float bias[6];
    #pragma unroll
    for (int s = 0; s < 6; ++s) bias[s] = b_hh[jj + 128 * s];

    if (tid < 32) reinterpret_cast<uint4*>(hs[0])[tid] = uint4{0, 0, 0, 0};
    __syncthreads();

    const int c0 = jj, c1 = jj + 128;
    float h0 = 0.0f, h1 = 0.0f;    // previous h for our two columns (all lanes)

    for (int t = 0; t < T_SEQ; ++t) {
        // issue xp loads early; consumed after the dot phase
        const float* xrow = xp + ((size_t)t * B_SZ + b) * G3;
        const float xr0 = xrow[c0],       xr1 = xrow[c1];
        const float xz0 = xrow[256 + c0], xz1 = xrow[256 + c1];
        const float xn0 = xrow[512 + c0], xn1 = xrow[512 + c1];

        // ---- partial dots over this thread's 64-wide k slice ----
        const uint4* hb = reinterpret_cast<const uint4*>(&hs[t & 1][q * 64]);
        float a0 = 0.f, a1 = 0.f, a2 = 0.f, a3 = 0.f, a4 = 0.f, a5 = 0.f;
        #pragma unroll
        for (int i8 = 0; i8 < 8; ++i8) {
            const uint4 hv = hb[(i8 + 2 * q) & 7];  // rotated: disjoint banks
            const half2v p0 = __builtin_bit_cast(half2v, hv.x);
            const half2v p1 = __builtin_bit_cast(half2v, hv.y);
            const half2v p2 = __builtin_bit_cast(half2v, hv.z);
            const half2v p3 = __builtin_bit_cast(half2v, hv.w);
            a0 = FDOT2(w[0][i8*4+0], p0, a0); a0 = FDOT2(w[0][i8*4+1], p1, a0);
            a0 = FDOT2(w[0][i8*4+2], p2, a0); a0 = FDOT2(w[0][i8*4+3], p3, a0);
            a1 = FDOT2(w[1][i8*4+0], p0, a1); a1 = FDOT2(w[1][i8*4+1], p1, a1);
            a1 = FDOT2(w[1][i8*4+2], p2, a1); a1 = FDOT2(w[1][i8*4+3], p3, a1);
            a2 = FDOT2(w[2][i8*4+0], p0, a2); a2 = FDOT2(w[2][i8*4+1], p1, a2);
            a2 = FDOT2(w[2][i8*4+2], p2, a2); a2 = FDOT2(w[2][i8*4+3], p3, a2);
            a3 = FDOT2(w[3][i8*4+0], p0, a3); a3 = FDOT2(w[3][i8*4+1], p1, a3);
            a3 = FDOT2(w[3][i8*4+2], p2, a3); a3 = FDOT2(w[3][i8*4+3], p3, a3);
            a4 = FDOT2(w[4][i8*4+0], p0, a4); a4 = FDOT2(w[4][i8*4+1], p1, a4);
            a4 = FDOT2(w[4][i8*4+2], p2, a4); a4 = FDOT2(w[4][i8*4+3], p3, a4);
            a5 = FDOT2(w[5][i8*4+0], p0, a5); a5 = FDOT2(w[5][i8*4+1], p1, a5);
            a5 = FDOT2(w[5][i8*4+2], p2, a5); a5 = FDOT2(w[5][i8*4+3], p3, a5);
        }

        // ---- quad butterfly reduce (DPP), then all lanes compute gates ----
        a0 += __shfl_xor(a0, 1); a0 += __shfl_xor(a0, 2);
        a1 += __shfl_xor(a1, 1); a1 += __shfl_xor(a1, 2);
        a2 += __shfl_xor(a2, 1); a2 += __shfl_xor(a2, 2);
        a3 += __shfl_xor(a3, 1); a3 += __shfl_xor(a3, 2);
        a4 += __shfl_xor(a4, 1); a4 += __shfl_xor(a4, 2);
        a5 += __shfl_xor(a5, 1); a5 += __shfl_xor(a5, 2);

        const float hr0 = a0 + bias[0], hr1 = a1 + bias[1];
        const float hz0 = a2 + bias[2], hz1 = a3 + bias[3];
        const float hn0 = a4 + bias[4], hn1 = a5 + bias[5];

        const float r0 = fast_sigmoid(xr0 + hr0);
        const float r1 = fast_sigmoid(xr1 + hr1);
        const float z0 = fast_sigmoid(xz0 + hz0);
        const float z1 = fast_sigmoid(xz1 + hz1);
        const float n0 = fast_tanh(xn0 + r0 * hn0);
        const float n1 = fast_tanh(xn1 + r1 * hn1);
        h0 = (1.0f - z0) * n0 + z0 * h0;
        h1 = (1.0f - z1) * n1 + z1 * h1;

        if (q == 0) {
            float* orow = out + ((size_t)t * B_SZ + b) * H_DIM;
            orow[c0] = h0;
            orow[c1] = h1;
            hs[(t + 1) & 1][c0] = (_Float16)h0;
            hs[(t + 1) & 1][c1] = (_Float16)h1;
        }
        __syncthreads();   // hs[(t+1)&1] visible; hs[t&1] free for overwrite
    }

    if (q == 0) {
        float* hl = out + (size_t)T_SEQ * B_SZ * H_DIM + (size_t)b * H_DIM;
        hl[c0] = h0;
        hl[c1] = h1;
    }
}

extern "C" void kernel_launch(void* const* d_in, const int* in_sizes, int n_in,
                              void* d_out, int out_size, void* d_ws, size_t ws_size,
                              hipStream_t stream) {
    const int*   input = (const int*)d_in[0];
    const float* emb   = (const float*)d_in[1];
    const float* W_ih  = (const float*)d_in[2];
    const float* W_hh  = (const float*)d_in[3];
    const float* b_ih  = (const float*)d_in[4];
    const float* b_hh  = (const float*)d_in[5];
    float* out = (float*)d_out;

    float* xp = (float*)d_ws;   // [T*B, 768] floats

    dim3 gridA(T_SEQ * B_SZ / BM, G3 / BN);   // (512, 12)
    xproj_kernel<<<gridA, 256, 0, stream>>>(input, emb, W_ih, b_ih, xp);

    gru_scan_kernel<<<B_SZ, 512, 0, stream>>>(xp, W_hh, b_hh, out);
}

// Round 4
// 961.926 us; speedup vs baseline: 1.0278x; 1.0278x over previous
//
#include <hip/hip_runtime.h>
#include <hip/hip_bf16.h>

// GRU: V=50000, E=256, H=256, B=64, T=512
// out: outputs[T,B,H] f32 then h_last[1,B,H] f32 (concat flat)

#define T_SEQ 512
#define B_SZ 64
#define E_DIM 256
#define H_DIM 256
#define G3 768   // 3*H

typedef _Float16 half2v __attribute__((ext_vector_type(2)));

#if __has_builtin(__builtin_amdgcn_fdot2)
#define FDOT2(a, b, c) __builtin_amdgcn_fdot2((a), (b), (c), false)
#else
#define FDOT2(a, b, c) ((c) + (float)(a).x * (float)(b).x + (float)(a).y * (float)(b).y)
#endif

// ---------------- Kernel A: x_proj = gather(emb, input) @ W_ih^T + b_ih ----
#define BM 64
#define BN 64
#define BK 32
#define LDSPAD 4

__global__ __launch_bounds__(256) void xproj_kernel(
    const int* __restrict__ input,
    const float* __restrict__ emb,
    const float* __restrict__ W_ih,
    const float* __restrict__ b_ih,
    float* __restrict__ xp)
{
    __shared__ float As[BM][BK + LDSPAD];
    __shared__ float Bs[BN][BK + LDSPAD];
    __shared__ int rowidx[BM];

    const int tid = threadIdx.x;
    const int m0 = blockIdx.x * BM;
    const int n0 = blockIdx.y * BN;

    if (tid < BM) {
        int m = m0 + tid;
        int t = m >> 6;
        int b = m & 63;
        rowidx[tid] = input[b * T_SEQ + t];
    }
    __syncthreads();

    float acc[4][4] = {};
    const int ty = tid >> 4;
    const int tx = tid & 15;

    for (int k0 = 0; k0 < E_DIM; k0 += BK) {
        #pragma unroll
        for (int i = 0; i < 2; ++i) {
            int f4 = tid * 2 + i;
            int row = f4 >> 3;
            int c4  = (f4 & 7) * 4;
            float4 v = *reinterpret_cast<const float4*>(
                emb + (size_t)rowidx[row] * E_DIM + k0 + c4);
            *reinterpret_cast<float4*>(&As[row][c4]) = v;
        }
        #pragma unroll
        for (int i = 0; i < 2; ++i) {
            int f4 = tid * 2 + i;
            int row = f4 >> 3;
            int c4  = (f4 & 7) * 4;
            float4 v = *reinterpret_cast<const float4*>(
                W_ih + (size_t)(n0 + row) * E_DIM + k0 + c4);
            *reinterpret_cast<float4*>(&Bs[row][c4]) = v;
        }
        __syncthreads();

        #pragma unroll
        for (int kk = 0; kk < BK; kk += 4) {
            float4 a[4], b[4];
            #pragma unroll
            for (int i = 0; i < 4; ++i)
                a[i] = *reinterpret_cast<const float4*>(&As[ty * 4 + i][kk]);
            #pragma unroll
            for (int j = 0; j < 4; ++j)
                b[j] = *reinterpret_cast<const float4*>(&Bs[tx * 4 + j][kk]);
            #pragma unroll
            for (int i = 0; i < 4; ++i)
                #pragma unroll
                for (int j = 0; j < 4; ++j)
                    acc[i][j] += a[i].x * b[j].x + a[i].y * b[j].y +
                                 a[i].z * b[j].z + a[i].w * b[j].w;
        }
        __syncthreads();
    }

    #pragma unroll
    for (int i = 0; i < 4; ++i) {
        int m = m0 + ty * 4 + i;
        int n = n0 + tx * 4;
        float4 o;
        o.x = acc[i][0] + b_ih[n + 0];
        o.y = acc[i][1] + b_ih[n + 1];
        o.z = acc[i][2] + b_ih[n + 2];
        o.w = acc[i][3] + b_ih[n + 3];
        *reinterpret_cast<float4*>(&xp[(size_t)m * G3 + n]) = o;
    }
}

// ---------------- Kernel B: GRU scan, weights PINNED in registers ----------
// 64 blocks (one per batch), 512 threads = 8 waves, launch_bounds(512,2)
// => 256-VGPR cap. Thread (jj = tid>>2, q = tid&3) owns 6 rows
// {jj + 128*s} x k-slice [64q,64q+64) of W_hh as 192 packed-f16 words.
// Each word is passed through an opaque `asm volatile("" : "+v")` after the
// prologue so the compiler CANNOT rematerialize the global loads inside the
// t-loop (R1/R2 failure mode: allocator chose re-load over residency).
// Quad-local __shfl_xor reduce; h double-buffered in LDS; 1 barrier/step.
__device__ __forceinline__ float fast_sigmoid(float x) {
    float e = __expf(-x);
    return __builtin_amdgcn_rcpf(1.0f + e);
}
__device__ __forceinline__ float fast_tanh(float x) {
    x = fminf(x, 8.0f);
    float e = __expf(2.0f * x);
    return (e - 1.0f) * __builtin_amdgcn_rcpf(e + 1.0f);
}

__global__ __launch_bounds__(512, 2) void gru_scan_kernel(
    const float* __restrict__ xp,    // [T*B, 768]
    const float* __restrict__ W_hh,  // [768, 256]
    const float* __restrict__ b_hh,  // [768]
    float* __restrict__ out)         // outputs [T*B*256] ++ h_last [64*256]
{
    const int b   = blockIdx.x;    // batch element
    const int tid = threadIdx.x;
    const int jj  = tid >> 2;      // 0..127 : column pair (jj, jj+128)
    const int q   = tid & 3;       // k-slice [64q, 64q+64)

    __shared__ __align__(16) _Float16 hs[2][H_DIM];  // double-buffered h (f16)

    // ---- prologue: weights -> registers, f16-packed, chunk-rotated by q ----
    uint32_t w[6][32];
    #pragma unroll
    for (int s = 0; s < 6; ++s) {
        const float* wr = W_hh + (size_t)(jj + 128 * s) * H_DIM + q * 64;
        #pragma unroll
        for (int i8 = 0; i8 < 8; ++i8) {
            const int src = ((i8 + 2 * q) & 7) * 8;   // rotated source chunk
            float4 f0 = *reinterpret_cast<const float4*>(wr + src);
            float4 f1 = *reinterpret_cast<const float4*>(wr + src + 4);
            w[s][i8*4+0] = __builtin_bit_cast(uint32_t, half2v{(_Float16)f0.x, (_Float16)f0.y});
            w[s][i8*4+1] = __builtin_bit_cast(uint32_t, half2v{(_Float16)f0.z, (_Float16)f0.w});
            w[s][i8*4+2] = __builtin_bit_cast(uint32_t, half2v{(_Float16)f1.x, (_Float16)f1.y});
            w[s][i8*4+3] = __builtin_bit_cast(uint32_t, half2v{(_Float16)f1.z, (_Float16)f1.w});
        }
    }
    // Opacity pin: values now originate from asm; loads cannot be re-issued
    // inside the t-loop, so the allocator must keep them live in VGPRs.
    #pragma unroll
    for (int s = 0; s < 6; ++s)
        #pragma unroll
        for (int i = 0; i < 32; ++i)
            asm volatile("" : "+v"(w[s][i]));

    float bias[6];
    #pragma unroll
    for (int s = 0; s < 6; ++s) bias[s] = b_hh[jj + 128 * s];

    if (tid < 32) reinterpret_cast<uint4*>(hs[0])[tid] = uint4{0, 0, 0, 0};
    __syncthreads();

    const int c0 = jj, c1 = jj + 128;
    float h0 = 0.0f, h1 = 0.0f;    // previous h for our two columns

    #define WH(s, i) __builtin_bit_cast(half2v, w[s][i])

    for (int t = 0; t < T_SEQ; ++t) {
        // issue xp loads early; consumed after the dot phase
        const float* xrow = xp + ((size_t)t * B_SZ + b) * G3;
        const float xr0 = xrow[c0],       xr1 = xrow[c1];
        const float xz0 = xrow[256 + c0], xz1 = xrow[256 + c1];
        const float xn0 = xrow[512 + c0], xn1 = xrow[512 + c1];

        // ---- partial dots over this thread's 64-wide k slice ----
        const uint4* hb = reinterpret_cast<const uint4*>(&hs[t & 1][q * 64]);
        float a0 = 0.f, a1 = 0.f, a2 = 0.f, a3 = 0.f, a4 = 0.f, a5 = 0.f;
        #pragma unroll
        for (int i8 = 0; i8 < 8; ++i8) {
            const uint4 hv = hb[(i8 + 2 * q) & 7];  // rotated: disjoint banks
            const half2v p0 = __builtin_bit_cast(half2v, hv.x);
            const half2v p1 = __builtin_bit_cast(half2v, hv.y);
            const half2v p2 = __builtin_bit_cast(half2v, hv.z);
            const half2v p3 = __builtin_bit_cast(half2v, hv.w);
            a0 = FDOT2(WH(0,i8*4+0), p0, a0); a0 = FDOT2(WH(0,i8*4+1), p1, a0);
            a0 = FDOT2(WH(0,i8*4+2), p2, a0); a0 = FDOT2(WH(0,i8*4+3), p3, a0);
            a1 = FDOT2(WH(1,i8*4+0), p0, a1); a1 = FDOT2(WH(1,i8*4+1), p1, a1);
            a1 = FDOT2(WH(1,i8*4+2), p2, a1); a1 = FDOT2(WH(1,i8*4+3), p3, a1);
            a2 = FDOT2(WH(2,i8*4+0), p0, a2); a2 = FDOT2(WH(2,i8*4+1), p1, a2);
            a2 = FDOT2(WH(2,i8*4+2), p2, a2); a2 = FDOT2(WH(2,i8*4+3), p3, a2);
            a3 = FDOT2(WH(3,i8*4+0), p0, a3); a3 = FDOT2(WH(3,i8*4+1), p1, a3);
            a3 = FDOT2(WH(3,i8*4+2), p2, a3); a3 = FDOT2(WH(3,i8*4+3), p3, a3);
            a4 = FDOT2(WH(4,i8*4+0), p0, a4); a4 = FDOT2(WH(4,i8*4+1), p1, a4);
            a4 = FDOT2(WH(4,i8*4+2), p2, a4); a4 = FDOT2(WH(4,i8*4+3), p3, a4);
            a5 = FDOT2(WH(5,i8*4+0), p0, a5); a5 = FDOT2(WH(5,i8*4+1), p1, a5);
            a5 = FDOT2(WH(5,i8*4+2), p2, a5); a5 = FDOT2(WH(5,i8*4+3), p3, a5);
        }

        // ---- quad butterfly reduce (DPP), then all lanes compute gates ----
        a0 += __shfl_xor(a0, 1); a0 += __shfl_xor(a0, 2);
        a1 += __shfl_xor(a1, 1); a1 += __shfl_xor(a1, 2);
        a2 += __shfl_xor(a2, 1); a2 += __shfl_xor(a2, 2);
        a3 += __shfl_xor(a3, 1); a3 += __shfl_xor(a3, 2);
        a4 += __shfl_xor(a4, 1); a4 += __shfl_xor(a4, 2);
        a5 += __shfl_xor(a5, 1); a5 += __shfl_xor(a5, 2);

        const float hr0 = a0 + bias[0], hr1 = a1 + bias[1];
        const float hz0 = a2 + bias[2], hz1 = a3 + bias[3];
        const float hn0 = a4 + bias[4], hn1 = a5 + bias[5];

        const float r0 = fast_sigmoid(xr0 + hr0);
        const float r1 = fast_sigmoid(xr1 + hr1);
        const float z0 = fast_sigmoid(xz0 + hz0);
        const float z1 = fast_sigmoid(xz1 + hz1);
        const float n0 = fast_tanh(xn0 + r0 * hn0);
        const float n1 = fast_tanh(xn1 + r1 * hn1);
        h0 = (1.0f - z0) * n0 + z0 * h0;
        h1 = (1.0f - z1) * n1 + z1 * h1;

        if (q == 0) {
            float* orow = out + ((size_t)t * B_SZ + b) * H_DIM;
            orow[c0] = h0;
            orow[c1] = h1;
            hs[(t + 1) & 1][c0] = (_Float16)h0;
            hs[(t + 1) & 1][c1] = (_Float16)h1;
        }
        __syncthreads();   // hs[(t+1)&1] visible; hs[t&1] free for overwrite
    }

    if (q == 0) {
        float* hl = out + (size_t)T_SEQ * B_SZ * H_DIM + (size_t)b * H_DIM;
        hl[c0] = h0;
        hl[c1] = h1;
    }
    #undef WH
}

extern "C" void kernel_launch(void* const* d_in, const int* in_sizes, int n_in,
                              void* d_out, int out_size, void* d_ws, size_t ws_size,
                              hipStream_t stream) {
    const int*   input = (const int*)d_in[0];
    const float* emb   = (const float*)d_in[1];
    const float* W_ih  = (const float*)d_in[2];
    const float* W_hh  = (const float*)d_in[3];
    const float* b_ih  = (const float*)d_in[4];
    const float* b_hh  = (const float*)d_in[5];
    float* out = (float*)d_out;

    float* xp = (float*)d_ws;   // [T*B, 768] floats

    dim3 gridA(T_SEQ * B_SZ / BM, G3 / BN);   // (512, 12)
    xproj_kernel<<<gridA, 256, 0, stream>>>(input, emb, W_ih, b_ih, xp);

    gru_scan_kernel<<<B_SZ, 512, 0, stream>>>(xp, W_hh, b_hh, out);
}

// Round 5
// 960.446 us; speedup vs baseline: 1.0294x; 1.0015x over previous
//
#include <hip/hip_runtime.h>
#include <hip/hip_bf16.h>

// GRU: V=50000, E=256, H=256, B=64, T=512
// out: outputs[T,B,H] f32 then h_last[1,B,H] f32 (concat flat)

#define T_SEQ 512
#define B_SZ 64
#define E_DIM 256
#define H_DIM 256
#define G3 768   // 3*H

typedef _Float16 half2v __attribute__((ext_vector_type(2)));

#if __has_builtin(__builtin_amdgcn_fdot2)
#define FDOT2(a, b, c) __builtin_amdgcn_fdot2((a), (b), (c), false)
#else
#define FDOT2(a, b, c) ((c) + (float)(a).x * (float)(b).x + (float)(a).y * (float)(b).y)
#endif

// ---------------- Kernel A: x_proj = gather(emb, input) @ W_ih^T + b_ih ----
#define BM 64
#define BN 64
#define BK 32
#define LDSPAD 4

__global__ __launch_bounds__(256) void xproj_kernel(
    const int* __restrict__ input,
    const float* __restrict__ emb,
    const float* __restrict__ W_ih,
    const float* __restrict__ b_ih,
    float* __restrict__ xp)
{
    __shared__ float As[BM][BK + LDSPAD];
    __shared__ float Bs[BN][BK + LDSPAD];
    __shared__ int rowidx[BM];

    const int tid = threadIdx.x;
    const int m0 = blockIdx.x * BM;
    const int n0 = blockIdx.y * BN;

    if (tid < BM) {
        int m = m0 + tid;
        int t = m >> 6;
        int b = m & 63;
        rowidx[tid] = input[b * T_SEQ + t];
    }
    __syncthreads();

    float acc[4][4] = {};
    const int ty = tid >> 4;
    const int tx = tid & 15;

    for (int k0 = 0; k0 < E_DIM; k0 += BK) {
        #pragma unroll
        for (int i = 0; i < 2; ++i) {
            int f4 = tid * 2 + i;
            int row = f4 >> 3;
            int c4  = (f4 & 7) * 4;
            float4 v = *reinterpret_cast<const float4*>(
                emb + (size_t)rowidx[row] * E_DIM + k0 + c4);
            *reinterpret_cast<float4*>(&As[row][c4]) = v;
        }
        #pragma unroll
        for (int i = 0; i < 2; ++i) {
            int f4 = tid * 2 + i;
            int row = f4 >> 3;
            int c4  = (f4 & 7) * 4;
            float4 v = *reinterpret_cast<const float4*>(
                W_ih + (size_t)(n0 + row) * E_DIM + k0 + c4);
            *reinterpret_cast<float4*>(&Bs[row][c4]) = v;
        }
        __syncthreads();

        #pragma unroll
        for (int kk = 0; kk < BK; kk += 4) {
            float4 a[4], b[4];
            #pragma unroll
            for (int i = 0; i < 4; ++i)
                a[i] = *reinterpret_cast<const float4*>(&As[ty * 4 + i][kk]);
            #pragma unroll
            for (int j = 0; j < 4; ++j)
                b[j] = *reinterpret_cast<const float4*>(&Bs[tx * 4 + j][kk]);
            #pragma unroll
            for (int i = 0; i < 4; ++i)
                #pragma unroll
                for (int j = 0; j < 4; ++j)
                    acc[i][j] += a[i].x * b[j].x + a[i].y * b[j].y +
                                 a[i].z * b[j].z + a[i].w * b[j].w;
        }
        __syncthreads();
    }

    #pragma unroll
    for (int i = 0; i < 4; ++i) {
        int m = m0 + ty * 4 + i;
        int n = n0 + tx * 4;
        float4 o;
        o.x = acc[i][0] + b_ih[n + 0];
        o.y = acc[i][1] + b_ih[n + 1];
        o.z = acc[i][2] + b_ih[n + 2];
        o.w = acc[i][3] + b_ih[n + 3];
        *reinterpret_cast<float4*>(&xp[(size_t)m * G3 + n]) = o;
    }
}

// ---------------- Kernel B: GRU scan, weights PINNED in registers ----------
// 64 blocks (one per batch), 512 threads = 8 waves.
// amdgpu_waves_per_eu(2,2): pins target occupancy to EXACTLY 2 waves/EU,
// giving the allocator a 256-VGPR cap AND removing the 4-waves/EU heuristic
// that caused spilling in R3/R4 (VGPR_Count stuck at 128, weights spilled
// to scratch in prologue and re-read every step).
// Thread (jj = tid>>2, q = tid&3) owns 6 rows {jj + 128*s} x k-slice
// [64q,64q+64) of W_hh as 192 packed-f16 words, pinned via opaque asm.
// Quad-local __shfl_xor reduce; h double-buffered in LDS; 1 barrier/step.
__device__ __forceinline__ float fast_sigmoid(float x) {
    float e = __expf(-x);
    return __builtin_amdgcn_rcpf(1.0f + e);
}
__device__ __forceinline__ float fast_tanh(float x) {
    x = fminf(x, 8.0f);
    float e = __expf(2.0f * x);
    return (e - 1.0f) * __builtin_amdgcn_rcpf(e + 1.0f);
}

__global__ __attribute__((amdgpu_flat_work_group_size(512, 512),
                          amdgpu_waves_per_eu(2, 2)))
void gru_scan_kernel(
    const float* __restrict__ xp,    // [T*B, 768]
    const float* __restrict__ W_hh,  // [768, 256]
    const float* __restrict__ b_hh,  // [768]
    float* __restrict__ out)         // outputs [T*B*256] ++ h_last [64*256]
{
    const int b   = blockIdx.x;    // batch element
    const int tid = threadIdx.x;
    const int jj  = tid >> 2;      // 0..127 : column pair (jj, jj+128)
    const int q   = tid & 3;       // k-slice [64q, 64q+64)

    __shared__ __align__(16) _Float16 hs[2][H_DIM];  // double-buffered h (f16)

    // ---- prologue: weights -> registers, f16-packed, chunk-rotated by q ----
    uint32_t w[6][32];
    #pragma unroll
    for (int s = 0; s < 6; ++s) {
        const float* wr = W_hh + (size_t)(jj + 128 * s) * H_DIM + q * 64;
        #pragma unroll
        for (int i8 = 0; i8 < 8; ++i8) {
            const int src = ((i8 + 2 * q) & 7) * 8;   // rotated source chunk
            float4 f0 = *reinterpret_cast<const float4*>(wr + src);
            float4 f1 = *reinterpret_cast<const float4*>(wr + src + 4);
            w[s][i8*4+0] = __builtin_bit_cast(uint32_t, half2v{(_Float16)f0.x, (_Float16)f0.y});
            w[s][i8*4+1] = __builtin_bit_cast(uint32_t, half2v{(_Float16)f0.z, (_Float16)f0.w});
            w[s][i8*4+2] = __builtin_bit_cast(uint32_t, half2v{(_Float16)f1.x, (_Float16)f1.y});
            w[s][i8*4+3] = __builtin_bit_cast(uint32_t, half2v{(_Float16)f1.z, (_Float16)f1.w});
        }
    }
    // Opacity pin: values originate from asm; loads cannot be re-issued
    // inside the t-loop.
    #pragma unroll
    for (int s = 0; s < 6; ++s)
        #pragma unroll
        for (int i = 0; i < 32; ++i)
            asm volatile("" : "+v"(w[s][i]));

    float bias[6];
    #pragma unroll
    for (int s = 0; s < 6; ++s) bias[s] = b_hh[jj + 128 * s];

    if (tid < 32) reinterpret_cast<uint4*>(hs[0])[tid] = uint4{0, 0, 0, 0};
    __syncthreads();

    const int c0 = jj, c1 = jj + 128;
    float h0 = 0.0f, h1 = 0.0f;    // previous h for our two columns

    #define WH(s, i) __builtin_bit_cast(half2v, w[s][i])

    for (int t = 0; t < T_SEQ; ++t) {
        // issue xp loads early; consumed after the dot phase
        const float* xrow = xp + ((size_t)t * B_SZ + b) * G3;
        const float xr0 = xrow[c0],       xr1 = xrow[c1];
        const float xz0 = xrow[256 + c0], xz1 = xrow[256 + c1];
        const float xn0 = xrow[512 + c0], xn1 = xrow[512 + c1];

        // ---- partial dots over this thread's 64-wide k slice ----
        const uint4* hb = reinterpret_cast<const uint4*>(&hs[t & 1][q * 64]);
        float a0 = 0.f, a1 = 0.f, a2 = 0.f, a3 = 0.f, a4 = 0.f, a5 = 0.f;
        #pragma unroll
        for (int i8 = 0; i8 < 8; ++i8) {
            const uint4 hv = hb[(i8 + 2 * q) & 7];  // rotated: disjoint banks
            const half2v p0 = __builtin_bit_cast(half2v, hv.x);
            const half2v p1 = __builtin_bit_cast(half2v, hv.y);
            const half2v p2 = __builtin_bit_cast(half2v, hv.z);
            const half2v p3 = __builtin_bit_cast(half2v, hv.w);
            a0 = FDOT2(WH(0,i8*4+0), p0, a0); a0 = FDOT2(WH(0,i8*4+1), p1, a0);
            a0 = FDOT2(WH(0,i8*4+2), p2, a0); a0 = FDOT2(WH(0,i8*4+3), p3, a0);
            a1 = FDOT2(WH(1,i8*4+0), p0, a1); a1 = FDOT2(WH(1,i8*4+1), p1, a1);
            a1 = FDOT2(WH(1,i8*4+2), p2, a1); a1 = FDOT2(WH(1,i8*4+3), p3, a1);
            a2 = FDOT2(WH(2,i8*4+0), p0, a2); a2 = FDOT2(WH(2,i8*4+1), p1, a2);
            a2 = FDOT2(WH(2,i8*4+2), p2, a2); a2 = FDOT2(WH(2,i8*4+3), p3, a2);
            a3 = FDOT2(WH(3,i8*4+0), p0, a3); a3 = FDOT2(WH(3,i8*4+1), p1, a3);
            a3 = FDOT2(WH(3,i8*4+2), p2, a3); a3 = FDOT2(WH(3,i8*4+3), p3, a3);
            a4 = FDOT2(WH(4,i8*4+0), p0, a4); a4 = FDOT2(WH(4,i8*4+1), p1, a4);
            a4 = FDOT2(WH(4,i8*4+2), p2, a4); a4 = FDOT2(WH(4,i8*4+3), p3, a4);
            a5 = FDOT2(WH(5,i8*4+0), p0, a5); a5 = FDOT2(WH(5,i8*4+1), p1, a5);
            a5 = FDOT2(WH(5,i8*4+2), p2, a5); a5 = FDOT2(WH(5,i8*4+3), p3, a5);
        }

        // ---- quad butterfly reduce (DPP), then all lanes compute gates ----
        a0 += __shfl_xor(a0, 1); a0 += __shfl_xor(a0, 2);
        a1 += __shfl_xor(a1, 1); a1 += __shfl_xor(a1, 2);
        a2 += __shfl_xor(a2, 1); a2 += __shfl_xor(a2, 2);
        a3 += __shfl_xor(a3, 1); a3 += __shfl_xor(a3, 2);
        a4 += __shfl_xor(a4, 1); a4 += __shfl_xor(a4, 2);
        a5 += __shfl_xor(a5, 1); a5 += __shfl_xor(a5, 2);

        const float hr0 = a0 + bias[0], hr1 = a1 + bias[1];
        const float hz0 = a2 + bias[2], hz1 = a3 + bias[3];
        const float hn0 = a4 + bias[4], hn1 = a5 + bias[5];

        const float r0 = fast_sigmoid(xr0 + hr0);
        const float r1 = fast_sigmoid(xr1 + hr1);
        const float z0 = fast_sigmoid(xz0 + hz0);
        const float z1 = fast_sigmoid(xz1 + hz1);
        const float n0 = fast_tanh(xn0 + r0 * hn0);
        const float n1 = fast_tanh(xn1 + r1 * hn1);
        h0 = (1.0f - z0) * n0 + z0 * h0;
        h1 = (1.0f - z1) * n1 + z1 * h1;

        if (q == 0) {
            float* orow = out + ((size_t)t * B_SZ + b) * H_DIM;
            orow[c0] = h0;
            orow[c1] = h1;
            hs[(t + 1) & 1][c0] = (_Float16)h0;
            hs[(t + 1) & 1][c1] = (_Float16)h1;
        }
        __syncthreads();   // hs[(t+1)&1] visible; hs[t&1] free for overwrite
    }

    if (q == 0) {
        float* hl = out + (size_t)T_SEQ * B_SZ * H_DIM + (size_t)b * H_DIM;
        hl[c0] = h0;
        hl[c1] = h1;
    }
    #undef WH
}

extern "C" void kernel_launch(void* const* d_in, const int* in_sizes, int n_in,
                              void* d_out, int out_size, void* d_ws, size_t ws_size,
                              hipStream_t stream) {
    const int*   input = (const int*)d_in[0];
    const float* emb   = (const float*)d_in[1];
    const float* W_ih  = (const float*)d_in[2];
    const float* W_hh  = (const float*)d_in[3];
    const float* b_ih  = (const float*)d_in[4];
    const float* b_hh  = (const float*)d_in[5];
    float* out = (float*)d_out;

    float* xp = (float*)d_ws;   // [T*B, 768] floats

    dim3 gridA(T_SEQ * B_SZ / BM, G3 / BN);   // (512, 12)
    xproj_kernel<<<gridA, 256, 0, stream>>>(input, emb, W_ih, b_ih, xp);

    gru_scan_kernel<<<B_SZ, 512, 0, stream>>>(xp, W_hh, b_hh, out);
}